// Round 1
// baseline (487.391 us; speedup 1.0000x reference)
//
#include <hip/hip_runtime.h>
#include <hip/hip_bf16.h>
#include <stdint.h>

// ---------------------------------------------------------------------------
// RegionLayer: 64 regions (8x8 grid of 8x8 patches), per-region:
//   hh = relu(BN(x));  y = conv3x3(hh, w[net]) + b[net] + x
// net = gj*(gi+1).  B=16, C=256, H=W=64, fp32 in/out; conv via bf16 MFMA.
// d_ws layout: [0, 75497472) bf16 weights [net][tap][co][ci]
//              [75497472, +33554432) bf16 hh [reg][b][px][c]
// ---------------------------------------------------------------------------

typedef __attribute__((ext_vector_type(8))) short bf16x8;
typedef __attribute__((ext_vector_type(8))) unsigned short u16x8;
typedef __attribute__((ext_vector_type(4))) float f32x4;

typedef const __attribute__((address_space(1))) unsigned int gu32;
typedef __attribute__((address_space(3))) unsigned int lu32;

__device__ __forceinline__ void g2l16(const void* g, void* l) {
  __builtin_amdgcn_global_load_lds((gu32*)g, (lu32*)l, 16, 0, 0);
}

__device__ __forceinline__ unsigned short f2bf(float f) {
  return __builtin_bit_cast(unsigned short, __float2bfloat16(f));
}

// ---------------------------------------------------------------------------
// Kernel 1: conv_w [net][co][ci][ky][kx] fp32  ->  wb [net][tap][co][ci] bf16
// Register transpose, no LDS. grid (32, 64) x 256 threads.
// Thread owns (co, ci0..ci0+7): loads 72 CONTIGUOUS floats (18 x float4),
// stores 9 x bf16x8 (16B/lane; wave = 1KB contiguous per tap).
// ---------------------------------------------------------------------------
__global__ __launch_bounds__(256) void wtrans_kernel(
    const float* __restrict__ w, __hip_bfloat16* __restrict__ wb) {
  const int net = blockIdx.y;                     // 0..63
  const int co = blockIdx.x * 8 + (threadIdx.x >> 5);  // 0..255
  const int ci0 = (threadIdx.x & 31) * 8;

  const float* src = w + (size_t)((net * 256 + co) * 256 + ci0) * 9;
  float b[72];
#pragma unroll
  for (int i = 0; i < 18; ++i) {
    f32x4 v = ((const f32x4*)src)[i];
    b[i * 4 + 0] = v[0];
    b[i * 4 + 1] = v[1];
    b[i * 4 + 2] = v[2];
    b[i * 4 + 3] = v[3];
  }
#pragma unroll
  for (int t = 0; t < 9; ++t) {
    u16x8 o;
#pragma unroll
    for (int j = 0; j < 8; ++j) o[j] = f2bf(b[j * 9 + t]);
    *(u16x8*)(wb + (size_t)((net * 9 + t) * 256 + co) * 256 + ci0) = o;
  }
}

// ---------------------------------------------------------------------------
// Kernel 2: BN+ReLU + NCHW -> per-region NHWC bf16.
// grid 4096 = (reg, b, cc): each block does one 64-channel chunk of one
// (region, batch): reads float4, LDS bf16 tile [64px][stride 66] (~2-way
// conflicts), writes bf16x8 (16B/lane).
// ---------------------------------------------------------------------------
__global__ __launch_bounds__(256) void bnrelu_kernel(
    const float* __restrict__ x, const float* __restrict__ gamma,
    const float* __restrict__ beta, const float* __restrict__ mean,
    const float* __restrict__ var, __hip_bfloat16* __restrict__ hh) {
  const int blk = blockIdx.x;
  const int cc = blk & 3;
  const int b = (blk >> 2) & 15;
  const int reg = blk >> 6;
  const int gi = reg >> 3, gj = reg & 7;
  const int net = gj * (gi + 1);
  const int tid = threadIdx.x;
  const int c0 = cc * 64;

  __shared__ float sc[64], sh[64];
  __shared__ unsigned short tile[64 * 66];

  if (tid < 64) {
    float g = gamma[net * 256 + c0 + tid];
    float bt = beta[net * 256 + c0 + tid];
    float m = mean[net * 256 + c0 + tid];
    float v = var[net * 256 + c0 + tid];
    float s = g * rsqrtf(v + 1e-5f);
    sc[tid] = s;
    sh[tid] = bt - m * s;
  }
  __syncthreads();

  const float* xb = x + (size_t)b * (256 * 4096) + (size_t)c0 * 4096 +
                    (gi * 8) * 64 + gj * 8;
#pragma unroll
  for (int i = 0; i < 4; ++i) {
    int idx = i * 256 + tid;
    int cl = idx >> 4;             // 0..63 channel within chunk
    int yy = (idx >> 1) & 7;       // patch row
    int hseg = idx & 1;            // which float4 of the 8-wide patch row
    f32x4 v = *(const f32x4*)(xb + (size_t)cl * 4096 + yy * 64 + hseg * 4);
    float s = sc[cl], t0 = sh[cl];
    int pxb = yy * 8 + hseg * 4;
#pragma unroll
    for (int j = 0; j < 4; ++j) {
      float hv = fmaxf(v[j] * s + t0, 0.f);
      tile[(pxb + j) * 66 + cl] = f2bf(hv);
    }
  }
  __syncthreads();

  __hip_bfloat16* hb = hh + (size_t)(reg * 16 + b) * (64 * 256) + c0;
#pragma unroll
  for (int k = 0; k < 2; ++k) {
    int o = k * 256 + tid;
    int px = o >> 3, cg = o & 7;
    u16x8 u;
#pragma unroll
    for (int j = 0; j < 8; ++j) u[j] = tile[px * 66 + cg * 8 + j];
    *(u16x8*)(hb + px * 256 + cg * 8) = u;
  }
}

// ---------------------------------------------------------------------------
// Kernel 3: implicit-GEMM conv via mfma_f32_16x16x32_bf16.
// Block = (region r, m-tile mt: batches 2mt..2mt+1 -> M rows 0..127,
//          n-tile nt: out channels nt*128..+127). 256 threads = 4 waves 2x2,
// each wave 64m x 64n (4x4 frags). K loop: 4 c-chunks x 9 taps x (kk=2).
// A/B 16KB tiles staged with global_load_lds(16B) using XOR swizzle
// slot_phys = (slot_log + row&7)&7  -> conflict-free ds_read_b128.
// Tap shift handled at A ds_read (shifted row + cndmask zero at patch edge).
// launch_bounds(256,4): VGPR=100<=128, LDS 4x32KB=128KB<=160KB -> 4 blk/CU
// (was 2) to overlap the per-tap vmcnt(0) barrier drains across blocks.
// ---------------------------------------------------------------------------
__global__ __launch_bounds__(256, 4) void conv_kernel(
    const __hip_bfloat16* __restrict__ hh,
    const __hip_bfloat16* __restrict__ wb,
    const float* __restrict__ xin,
    const float* __restrict__ cbias,
    float* __restrict__ outp) {
  __shared__ __align__(16) char sA[16384];
  __shared__ __align__(16) char sB[16384];

  const int bx = blockIdx.x;
  const int r = bx >> 4;
  const int mt = bx & 7;
  const int nt = (bx >> 3) & 1;
  const int gi = r >> 3, gj = r & 7;
  const int net = gj * (gi + 1);

  const int tid = threadIdx.x;
  const int lane = tid & 63;
  const int wv = tid >> 6;
  const int wm = (wv & 1) * 64;
  const int wn = (wv >> 1) * 64;
  const int ln = lane & 15;
  const int q = lane >> 4;

  const __hip_bfloat16* Aslab = hh + (size_t)(r * 16 + mt * 2) * (64 * 256);
  const __hip_bfloat16* Bbase =
      wb + (size_t)(net * 9) * (256 * 256) + (size_t)(nt * 128) * 256;

  // per-lane decode of the 4 A-fragment rows (output pixels)
  int bl[4], py[4], pxr[4];
#pragma unroll
  for (int mf = 0; mf < 4; ++mf) {
    int m = wm + mf * 16 + ln;
    bl[mf] = m >> 6;
    py[mf] = (m >> 3) & 7;
    pxr[mf] = m & 7;
  }
  // B fragment LDS byte offsets (constant across whole K loop)
  int boff[4][2];
#pragma unroll
  for (int nf = 0; nf < 4; ++nf) {
    int nrow = wn + nf * 16 + ln;
#pragma unroll
    for (int kk = 0; kk < 2; ++kk) {
      int sl = kk * 4 + q;
      int sp = (sl + (nrow & 7)) & 7;
      boff[nf][kk] = nrow * 128 + sp * 16;
    }
  }

  f32x4 acc[4][4];
#pragma unroll
  for (int mf = 0; mf < 4; ++mf)
#pragma unroll
    for (int nf = 0; nf < 4; ++nf)
      acc[mf][nf] = (f32x4){0.f, 0.f, 0.f, 0.f};

  const bf16x8 zero8 = {0, 0, 0, 0, 0, 0, 0, 0};

#pragma unroll 1
  for (int cc = 0; cc < 4; ++cc) {
    const int c0 = cc * 64;
    // stage A: 128 rows x 64ch bf16 = 16KB, swizzled source addressing
#pragma unroll
    for (int i = 0; i < 4; ++i) {
      int slot = i * 256 + tid;
      int row = slot >> 3, sp = slot & 7;
      int sl = (sp - (row & 7)) & 7;
      g2l16(Aslab + (size_t)row * 256 + c0 + sl * 8, sA + slot * 16);
    }
#pragma unroll
    for (int tap = 0; tap < 9; ++tap) {
      const int dy = tap / 3 - 1, dx = tap % 3 - 1;
      const __hip_bfloat16* Btap = Bbase + (size_t)tap * (256 * 256);
#pragma unroll
      for (int i = 0; i < 4; ++i) {
        int slot = i * 256 + tid;
        int row = slot >> 3, sp = slot & 7;
        int sl = (sp - (row & 7)) & 7;
        g2l16(Btap + (size_t)row * 256 + c0 + sl * 8, sB + slot * 16);
      }
      __syncthreads();  // drains vmcnt: A+B staging visible

      int arow[4], avalid[4];
#pragma unroll
      for (int mf = 0; mf < 4; ++mf) {
        int sy = py[mf] + dy, sx = pxr[mf] + dx;
        int v = ((unsigned)sy < 8u) & ((unsigned)sx < 8u);
        avalid[mf] = v;
        arow[mf] = (bl[mf] << 6) + (v ? (sy * 8 + sx) : 0);
      }
#pragma unroll
      for (int kk = 0; kk < 2; ++kk) {
        bf16x8 afr[4], bfr[4];
#pragma unroll
        for (int mf = 0; mf < 4; ++mf) {
          int row = arow[mf];
          int sp = ((kk * 4 + q) + (row & 7)) & 7;
          bf16x8 v = *(const bf16x8*)(sA + row * 128 + sp * 16);
          afr[mf] = avalid[mf] ? v : zero8;
        }
#pragma unroll
        for (int nf = 0; nf < 4; ++nf)
          bfr[nf] = *(const bf16x8*)(sB + boff[nf][kk]);
#pragma unroll
        for (int mf = 0; mf < 4; ++mf)
#pragma unroll
          for (int nf = 0; nf < 4; ++nf)
            acc[mf][nf] = __builtin_amdgcn_mfma_f32_16x16x32_bf16(
                afr[mf], bfr[nf], acc[mf][nf], 0, 0, 0);
      }
      __syncthreads();  // compute reads done; safe to overwrite LDS
    }
  }

  // Epilogue: D col = lane&15 (n), row = q*4+reg (m). Each lane's 4 regs are
  // 4 consecutive x-pixels -> aligned float4 residual load + store.
  const int nbase = nt * 128 + wn;
#pragma unroll
  for (int nf = 0; nf < 4; ++nf) {
    const int n = nbase + nf * 16 + ln;
    const float cb = cbias[net * 256 + n];
#pragma unroll
    for (int mf = 0; mf < 4; ++mf) {
      int mloc = wm + mf * 16 + q * 4;
      int b = mt * 2 + (mloc >> 6);
      int px = mloc & 63;
      int yy = px >> 3, x0 = px & 7;
      size_t off =
          (((size_t)b * 256 + n) * 64 + (gi * 8 + yy)) * 64 + (gj * 8 + x0);
      f32x4 res = *(const f32x4*)(xin + off);
      f32x4 o = acc[mf][nf];
      o = o + res;
      o = o + cb;
      *(f32x4*)(outp + off) = o;
    }
  }
}

// ---------------------------------------------------------------------------
extern "C" void kernel_launch(void* const* d_in, const int* in_sizes, int n_in,
                              void* d_out, int out_size, void* d_ws,
                              size_t ws_size, hipStream_t stream) {
  const float* x      = (const float*)d_in[0];
  const float* gamma  = (const float*)d_in[1];
  const float* beta   = (const float*)d_in[2];
  const float* mean   = (const float*)d_in[3];
  const float* var    = (const float*)d_in[4];
  const float* conv_w = (const float*)d_in[5];
  const float* conv_b = (const float*)d_in[6];
  float* out = (float*)d_out;

  __hip_bfloat16* wb = (__hip_bfloat16*)d_ws;                       // 75497472 B
  __hip_bfloat16* hh = (__hip_bfloat16*)((char*)d_ws + 75497472);   // 33554432 B

  wtrans_kernel<<<dim3(32, 64), 256, 0, stream>>>(conv_w, wb);
  bnrelu_kernel<<<4096, 256, 0, stream>>>(x, gamma, beta, mean, var, hh);
  conv_kernel<<<1024, 256, 0, stream>>>(hh, wb, x, conv_b, out);
}

// Round 2
// 412.491 us; speedup vs baseline: 1.1816x; 1.1816x over previous
//
#include <hip/hip_runtime.h>
#include <hip/hip_bf16.h>
#include <stdint.h>

// ---------------------------------------------------------------------------
// RegionLayer: 64 regions (8x8 grid of 8x8 patches), per-region:
//   hh = relu(BN(x));  y = conv3x3(hh, w[net]) + b[net] + x
// net = gj*(gi+1).  B=16, C=256, H=W=64, fp32 in/out; conv via bf16 MFMA.
// d_ws layout: [0, 75497472) bf16 weights [net][tap][co][ci]
//              [75497472, +33554432) bf16 hh [reg][b][px][c]
// ---------------------------------------------------------------------------

typedef __attribute__((ext_vector_type(8))) short bf16x8;
typedef __attribute__((ext_vector_type(8))) unsigned short u16x8;
typedef __attribute__((ext_vector_type(4))) float f32x4;

typedef const __attribute__((address_space(1))) unsigned int gu32;
typedef __attribute__((address_space(3))) unsigned int lu32;

__device__ __forceinline__ void g2l16(const void* g, void* l) {
  __builtin_amdgcn_global_load_lds((gu32*)g, (lu32*)l, 16, 0, 0);
}

__device__ __forceinline__ unsigned short f2bf(float f) {
  return __builtin_bit_cast(unsigned short, __float2bfloat16(f));
}

// ---------------------------------------------------------------------------
// Kernel 1: conv_w [net][co][ci][ky][kx] fp32  ->  wb [net][tap][co][ci] bf16
// Register transpose, no LDS. grid (32, 64) x 256 threads.
// ---------------------------------------------------------------------------
__global__ __launch_bounds__(256) void wtrans_kernel(
    const float* __restrict__ w, __hip_bfloat16* __restrict__ wb) {
  const int net = blockIdx.y;                     // 0..63
  const int co = blockIdx.x * 8 + (threadIdx.x >> 5);  // 0..255
  const int ci0 = (threadIdx.x & 31) * 8;

  const float* src = w + (size_t)((net * 256 + co) * 256 + ci0) * 9;
  float b[72];
#pragma unroll
  for (int i = 0; i < 18; ++i) {
    f32x4 v = ((const f32x4*)src)[i];
    b[i * 4 + 0] = v[0];
    b[i * 4 + 1] = v[1];
    b[i * 4 + 2] = v[2];
    b[i * 4 + 3] = v[3];
  }
#pragma unroll
  for (int t = 0; t < 9; ++t) {
    u16x8 o;
#pragma unroll
    for (int j = 0; j < 8; ++j) o[j] = f2bf(b[j * 9 + t]);
    *(u16x8*)(wb + (size_t)((net * 9 + t) * 256 + co) * 256 + ci0) = o;
  }
}

// ---------------------------------------------------------------------------
// Kernel 2: BN+ReLU + NCHW -> per-region NHWC bf16.
// grid 4096 = (reg, b, cc); float4 reads, bf16 LDS tile, u16x8 stores.
// ---------------------------------------------------------------------------
__global__ __launch_bounds__(256) void bnrelu_kernel(
    const float* __restrict__ x, const float* __restrict__ gamma,
    const float* __restrict__ beta, const float* __restrict__ mean,
    const float* __restrict__ var, __hip_bfloat16* __restrict__ hh) {
  const int blk = blockIdx.x;
  const int cc = blk & 3;
  const int b = (blk >> 2) & 15;
  const int reg = blk >> 6;
  const int gi = reg >> 3, gj = reg & 7;
  const int net = gj * (gi + 1);
  const int tid = threadIdx.x;
  const int c0 = cc * 64;

  __shared__ float sc[64], sh[64];
  __shared__ unsigned short tile[64 * 66];

  if (tid < 64) {
    float g = gamma[net * 256 + c0 + tid];
    float bt = beta[net * 256 + c0 + tid];
    float m = mean[net * 256 + c0 + tid];
    float v = var[net * 256 + c0 + tid];
    float s = g * rsqrtf(v + 1e-5f);
    sc[tid] = s;
    sh[tid] = bt - m * s;
  }
  __syncthreads();

  const float* xb = x + (size_t)b * (256 * 4096) + (size_t)c0 * 4096 +
                    (gi * 8) * 64 + gj * 8;
#pragma unroll
  for (int i = 0; i < 4; ++i) {
    int idx = i * 256 + tid;
    int cl = idx >> 4;             // 0..63 channel within chunk
    int yy = (idx >> 1) & 7;       // patch row
    int hseg = idx & 1;            // which float4 of the 8-wide patch row
    f32x4 v = *(const f32x4*)(xb + (size_t)cl * 4096 + yy * 64 + hseg * 4);
    float s = sc[cl], t0 = sh[cl];
    int pxb = yy * 8 + hseg * 4;
#pragma unroll
    for (int j = 0; j < 4; ++j) {
      float hv = fmaxf(v[j] * s + t0, 0.f);
      tile[(pxb + j) * 66 + cl] = f2bf(hv);
    }
  }
  __syncthreads();

  __hip_bfloat16* hb = hh + (size_t)(reg * 16 + b) * (64 * 256) + c0;
#pragma unroll
  for (int k = 0; k < 2; ++k) {
    int o = k * 256 + tid;
    int px = o >> 3, cg = o & 7;
    u16x8 u;
#pragma unroll
    for (int j = 0; j < 8; ++j) u[j] = tile[px * 66 + cg * 8 + j];
    *(u16x8*)(hb + px * 256 + cg * 8) = u;
  }
}

// ---------------------------------------------------------------------------
// Kernel 3: implicit-GEMM conv via mfma_f32_16x16x32_bf16.
// Block = (region r, m-tile mt: batches 2mt..2mt+1 -> M rows 0..127,
//          n-tile nt: out channels nt*128..+127). 256 threads = 4 waves 2x2,
// each wave 64m x 64n (4x4 frags). K loop: 4 c-chunks x 3 tap-GROUPS x 3 taps.
//
// R2 change vs R0: B staged 3 taps per sync-pair (sB = 3x16KB = 48KB), so each
// vmcnt(0) barrier drain covers 96 MFMA instead of 32 (12 sync-pairs/block vs
// 40). LDS 16KB(A)+48KB(B)=64KB -> 2 blocks/CU (128<=160KB), same overlap as
// the proven R0 config.  launch_bounds(256,2): (256,4) measured -56% (L2
// thrash: WRITE_SIZE 80->166MB, VGPR squeezed 100->64) — do not raise.
// XOR swizzle slot_phys=(slot_log+row&7)&7 -> conflict-free ds_read_b128.
// Tap shift handled at A ds_read (shifted row + cndmask zero at patch edge);
// with tap = g*3+tt: dy = g-1, dx = tt-1.
// ---------------------------------------------------------------------------
__global__ __launch_bounds__(256, 2) void conv_kernel(
    const __hip_bfloat16* __restrict__ hh,
    const __hip_bfloat16* __restrict__ wb,
    const float* __restrict__ xin,
    const float* __restrict__ cbias,
    float* __restrict__ outp) {
  __shared__ __align__(16) char sA[16384];
  __shared__ __align__(16) char sB[49152];

  const int bx = blockIdx.x;
  const int r = bx >> 4;
  const int mt = bx & 7;
  const int nt = (bx >> 3) & 1;
  const int gi = r >> 3, gj = r & 7;
  const int net = gj * (gi + 1);

  const int tid = threadIdx.x;
  const int lane = tid & 63;
  const int wv = tid >> 6;
  const int wm = (wv & 1) * 64;
  const int wn = (wv >> 1) * 64;
  const int ln = lane & 15;
  const int q = lane >> 4;

  const __hip_bfloat16* Aslab = hh + (size_t)(r * 16 + mt * 2) * (64 * 256);
  const __hip_bfloat16* Bbase =
      wb + (size_t)(net * 9) * (256 * 256) + (size_t)(nt * 128) * 256;

  // per-lane decode of the 4 A-fragment rows (output pixels)
  int bl[4], py[4], pxr[4];
#pragma unroll
  for (int mf = 0; mf < 4; ++mf) {
    int m = wm + mf * 16 + ln;
    bl[mf] = m >> 6;
    py[mf] = (m >> 3) & 7;
    pxr[mf] = m & 7;
  }
  // B fragment LDS byte offsets within one 16KB tap tile (constant all K loop)
  int boff[4][2];
#pragma unroll
  for (int nf = 0; nf < 4; ++nf) {
    int nrow = wn + nf * 16 + ln;
#pragma unroll
    for (int kk = 0; kk < 2; ++kk) {
      int sl = kk * 4 + q;
      int sp = (sl + (nrow & 7)) & 7;
      boff[nf][kk] = nrow * 128 + sp * 16;
    }
  }

  f32x4 acc[4][4];
#pragma unroll
  for (int mf = 0; mf < 4; ++mf)
#pragma unroll
    for (int nf = 0; nf < 4; ++nf)
      acc[mf][nf] = (f32x4){0.f, 0.f, 0.f, 0.f};

  const bf16x8 zero8 = {0, 0, 0, 0, 0, 0, 0, 0};

#pragma unroll 1
  for (int cc = 0; cc < 4; ++cc) {
    const int c0 = cc * 64;
    // stage A: 128 rows x 64ch bf16 = 16KB, swizzled source addressing
#pragma unroll
    for (int i = 0; i < 4; ++i) {
      int slot = i * 256 + tid;
      int row = slot >> 3, sp = slot & 7;
      int sl = (sp - (row & 7)) & 7;
      g2l16(Aslab + (size_t)row * 256 + c0 + sl * 8, sA + slot * 16);
    }
#pragma unroll 1
    for (int g = 0; g < 3; ++g) {
      // stage B for taps g*3 .. g*3+2 (3 x 16KB)
#pragma unroll
      for (int tt = 0; tt < 3; ++tt) {
        const __hip_bfloat16* Btap =
            Bbase + (size_t)(g * 3 + tt) * (256 * 256);
#pragma unroll
        for (int i = 0; i < 4; ++i) {
          int slot = i * 256 + tid;
          int row = slot >> 3, sp = slot & 7;
          int sl = (sp - (row & 7)) & 7;
          g2l16(Btap + (size_t)row * 256 + c0 + sl * 8,
                sB + tt * 16384 + slot * 16);
        }
      }
      __syncthreads();  // one vmcnt(0) drain covers A(+first group) + 3 B taps

#pragma unroll
      for (int tt = 0; tt < 3; ++tt) {
        const int dy = g - 1, dx = tt - 1;
        const char* sBt = sB + tt * 16384;

        int arow[4], avalid[4];
#pragma unroll
        for (int mf = 0; mf < 4; ++mf) {
          int sy = py[mf] + dy, sx = pxr[mf] + dx;
          int v = ((unsigned)sy < 8u) & ((unsigned)sx < 8u);
          avalid[mf] = v;
          arow[mf] = (bl[mf] << 6) + (v ? (sy * 8 + sx) : 0);
        }
#pragma unroll
        for (int kk = 0; kk < 2; ++kk) {
          bf16x8 afr[4], bfr[4];
#pragma unroll
          for (int mf = 0; mf < 4; ++mf) {
            int row = arow[mf];
            int sp = ((kk * 4 + q) + (row & 7)) & 7;
            bf16x8 v = *(const bf16x8*)(sA + row * 128 + sp * 16);
            afr[mf] = avalid[mf] ? v : zero8;
          }
#pragma unroll
          for (int nf = 0; nf < 4; ++nf)
            bfr[nf] = *(const bf16x8*)(sBt + boff[nf][kk]);
#pragma unroll
          for (int mf = 0; mf < 4; ++mf)
#pragma unroll
            for (int nf = 0; nf < 4; ++nf)
              acc[mf][nf] = __builtin_amdgcn_mfma_f32_16x16x32_bf16(
                  afr[mf], bfr[nf], acc[mf][nf], 0, 0, 0);
        }
      }
      __syncthreads();  // compute reads done; safe to overwrite sB (and sA at cc end)
    }
  }

  // Epilogue: D col = lane&15 (n), row = q*4+reg (m). Each lane's 4 regs are
  // 4 consecutive x-pixels -> aligned float4 residual load + store.
  const int nbase = nt * 128 + wn;
#pragma unroll
  for (int nf = 0; nf < 4; ++nf) {
    const int n = nbase + nf * 16 + ln;
    const float cb = cbias[net * 256 + n];
#pragma unroll
    for (int mf = 0; mf < 4; ++mf) {
      int mloc = wm + mf * 16 + q * 4;
      int b = mt * 2 + (mloc >> 6);
      int px = mloc & 63;
      int yy = px >> 3, x0 = px & 7;
      size_t off =
          (((size_t)b * 256 + n) * 64 + (gi * 8 + yy)) * 64 + (gj * 8 + x0);
      f32x4 res = *(const f32x4*)(xin + off);
      f32x4 o = acc[mf][nf];
      o = o + res;
      o = o + cb;
      *(f32x4*)(outp + off) = o;
    }
  }
}

// ---------------------------------------------------------------------------
extern "C" void kernel_launch(void* const* d_in, const int* in_sizes, int n_in,
                              void* d_out, int out_size, void* d_ws,
                              size_t ws_size, hipStream_t stream) {
  const float* x      = (const float*)d_in[0];
  const float* gamma  = (const float*)d_in[1];
  const float* beta   = (const float*)d_in[2];
  const float* mean   = (const float*)d_in[3];
  const float* var    = (const float*)d_in[4];
  const float* conv_w = (const float*)d_in[5];
  const float* conv_b = (const float*)d_in[6];
  float* out = (float*)d_out;

  __hip_bfloat16* wb = (__hip_bfloat16*)d_ws;                       // 75497472 B
  __hip_bfloat16* hh = (__hip_bfloat16*)((char*)d_ws + 75497472);   // 33554432 B

  wtrans_kernel<<<dim3(32, 64), 256, 0, stream>>>(conv_w, wb);
  bnrelu_kernel<<<4096, 256, 0, stream>>>(x, gamma, beta, mean, var, hh);
  conv_kernel<<<1024, 256, 0, stream>>>(hh, wb, x, conv_b, out);
}

// Round 3
// 402.782 us; speedup vs baseline: 1.2101x; 1.0241x over previous
//
#include <hip/hip_runtime.h>
#include <hip/hip_bf16.h>
#include <stdint.h>

// ---------------------------------------------------------------------------
// RegionLayer: 64 regions (8x8 grid of 8x8 patches), per-region:
//   hh = relu(BN(x));  y = conv3x3(hh, w[net]) + b[net] + x
// net = gj*(gi+1).  B=16, C=256, H=W=64, fp32 in/out; conv via bf16 MFMA.
// d_ws layout: [0, 75497472) bf16 weights [net][tap][co][ci]
//              [75497472, +33554432) bf16 hh [reg][b][px][c]
// ---------------------------------------------------------------------------

typedef __attribute__((ext_vector_type(8))) short bf16x8;
typedef __attribute__((ext_vector_type(8))) unsigned short u16x8;
typedef __attribute__((ext_vector_type(4))) float f32x4;

typedef const __attribute__((address_space(1))) unsigned int gu32;
typedef __attribute__((address_space(3))) unsigned int lu32;

__device__ __forceinline__ void g2l16(const void* g, void* l) {
  __builtin_amdgcn_global_load_lds((gu32*)g, (lu32*)l, 16, 0, 0);
}

__device__ __forceinline__ unsigned short f2bf(float f) {
  return __builtin_bit_cast(unsigned short, __float2bfloat16(f));
}

// ---------------------------------------------------------------------------
// Kernel 1: conv_w [net][co][ci][ky][kx] fp32  ->  wb [net][tap][co][ci] bf16
// R3: LDS transpose. Block = (net, 8 co values). Reads 72KB CONTIGUOUS
// (18 f32x4/thread, perfect per-instruction coalescing — R1's 288B lane
// stride was the defect), scatters bf16 into LDS [t][co][ci] (~4-way write
// conflicts, cheap), writes 9 x 4KB contiguous runs (u16x8; LDS read side is
// flat 1KB/wave = conflict-free).
// ---------------------------------------------------------------------------
__global__ __launch_bounds__(256) void wtrans_kernel(
    const float* __restrict__ w, __hip_bfloat16* __restrict__ wb) {
  const int net = blockIdx.y;   // 0..63
  const int cog = blockIdx.x;   // 0..31 -> co0 = cog*8
  const int tid = threadIdx.x;

  __shared__ unsigned short sw[9 * 8 * 256];  // [t][co_sub][ci] = 36864 B

  const float* src = w + (size_t)(net * 256 + cog * 8) * (256 * 9);
#pragma unroll
  for (int i = 0; i < 18; ++i) {
    int c4 = i * 256 + tid;                // f32x4 index within 72KB blob
    f32x4 v = ((const f32x4*)src)[c4];
    int p = c4 * 4;                        // flat float index
#pragma unroll
    for (int j = 0; j < 4; ++j) {
      int pp = p + j;
      int cos = pp / 2304;                 // co_sub 0..7  (2304 = 256*9)
      int rem = pp - cos * 2304;
      int ci = rem / 9;
      int t = rem - ci * 9;
      sw[(t * 8 + cos) * 256 + ci] = f2bf(v[j]);
    }
  }
  __syncthreads();

  __hip_bfloat16* dst =
      wb + (size_t)(net * 9) * (256 * 256) + (size_t)(cog * 8) * 256;
  const int e0 = tid * 8;        // 0..2040 within one tap's 8co x 256ci
  const int cos = e0 >> 8, ci0 = e0 & 255;
#pragma unroll
  for (int t = 0; t < 9; ++t) {
    u16x8 u;
#pragma unroll
    for (int j = 0; j < 8; ++j) u[j] = sw[(t * 8 + cos) * 256 + ci0 + j];
    *(u16x8*)(dst + (size_t)t * (256 * 256) + cos * 256 + ci0) = u;
  }
}

// ---------------------------------------------------------------------------
// Kernel 2: BN+ReLU + NCHW -> per-region NHWC bf16.  (unchanged from R1/R2)
// grid 4096 = (reg, b, cc); float4 reads, bf16 LDS tile, u16x8 stores.
// ---------------------------------------------------------------------------
__global__ __launch_bounds__(256) void bnrelu_kernel(
    const float* __restrict__ x, const float* __restrict__ gamma,
    const float* __restrict__ beta, const float* __restrict__ mean,
    const float* __restrict__ var, __hip_bfloat16* __restrict__ hh) {
  const int blk = blockIdx.x;
  const int cc = blk & 3;
  const int b = (blk >> 2) & 15;
  const int reg = blk >> 6;
  const int gi = reg >> 3, gj = reg & 7;
  const int net = gj * (gi + 1);
  const int tid = threadIdx.x;
  const int c0 = cc * 64;

  __shared__ float sc[64], sh[64];
  __shared__ unsigned short tile[64 * 66];

  if (tid < 64) {
    float g = gamma[net * 256 + c0 + tid];
    float bt = beta[net * 256 + c0 + tid];
    float m = mean[net * 256 + c0 + tid];
    float v = var[net * 256 + c0 + tid];
    float s = g * rsqrtf(v + 1e-5f);
    sc[tid] = s;
    sh[tid] = bt - m * s;
  }
  __syncthreads();

  const float* xb = x + (size_t)b * (256 * 4096) + (size_t)c0 * 4096 +
                    (gi * 8) * 64 + gj * 8;
#pragma unroll
  for (int i = 0; i < 4; ++i) {
    int idx = i * 256 + tid;
    int cl = idx >> 4;
    int yy = (idx >> 1) & 7;
    int hseg = idx & 1;
    f32x4 v = *(const f32x4*)(xb + (size_t)cl * 4096 + yy * 64 + hseg * 4);
    float s = sc[cl], t0 = sh[cl];
    int pxb = yy * 8 + hseg * 4;
#pragma unroll
    for (int j = 0; j < 4; ++j) {
      float hv = fmaxf(v[j] * s + t0, 0.f);
      tile[(pxb + j) * 66 + cl] = f2bf(hv);
    }
  }
  __syncthreads();

  __hip_bfloat16* hb = hh + (size_t)(reg * 16 + b) * (64 * 256) + c0;
#pragma unroll
  for (int k = 0; k < 2; ++k) {
    int o = k * 256 + tid;
    int px = o >> 3, cg = o & 7;
    u16x8 u;
#pragma unroll
    for (int j = 0; j < 8; ++j) u[j] = tile[px * 66 + cg * 8 + j];
    *(u16x8*)(hb + px * 256 + cg * 8) = u;
  }
}

// ---------------------------------------------------------------------------
// Kernel 3: implicit-GEMM conv via mfma_f32_16x16x32_bf16.
// Block = (region r, m-tile mt, n-tile nt). 256 threads = 4 waves 2x2,
// each wave 64m x 64n (4x4 frags).
//
// R3: counted-vmcnt ring pipeline (T3/T4). sB = 3 x 16KB tap-slot ring;
// depth-2 prefetch. Per phase t (fully unrolled, 9 per cc):
//   issue tap t+2 -> slot (t+2)%3   [slot safe: tap t-1 compute done at
//                                    phase t-1's post-barrier]
//   s_waitcnt vmcnt(8)              [2 tiles stay IN FLIGHT across barrier —
//                                    never drains to 0 in steady state]
//   s_barrier                       [all waves' tap-t loads landed]
//   32 MFMA (setprio 1..0)          [T5]
//   s_barrier                       [reads done -> slot reusable]
// cc boundary: A + tap0' + tap1' issued after final barrier (4 bubbles total
// vs R2's 12 full vmcnt(0) drains).  LDS 16+48=64KB, 2 blk/CU
// (launch_bounds(256,2); (256,4) measured -56% in R1 — L2 write thrash).
// T1: XCD-bijective swizzle (bx%8)*128+bx/8 — the 16 blocks sharing one
// net's 1.18MB weights land on one XCD's L2.
// XOR swizzle slot_phys=(slot_log+row&7)&7 -> conflict-free ds_read_b128.
// ---------------------------------------------------------------------------
__global__ __launch_bounds__(256, 2) void conv_kernel(
    const __hip_bfloat16* __restrict__ hh,
    const __hip_bfloat16* __restrict__ wb,
    const float* __restrict__ xin,
    const float* __restrict__ cbias,
    float* __restrict__ outp) {
  __shared__ __align__(16) char sA[16384];
  __shared__ __align__(16) char sB[49152];

  const int bxr = blockIdx.x;
  const int bx = (bxr & 7) * 128 + (bxr >> 3);  // XCD-bijective (1024 = 8*128)
  const int r = bx >> 4;
  const int mt = bx & 7;
  const int nt = (bx >> 3) & 1;
  const int gi = r >> 3, gj = r & 7;
  const int net = gj * (gi + 1);

  const int tid = threadIdx.x;
  const int lane = tid & 63;
  const int wv = tid >> 6;
  const int wm = (wv & 1) * 64;
  const int wn = (wv >> 1) * 64;
  const int ln = lane & 15;
  const int q = lane >> 4;

  const __hip_bfloat16* Aslab = hh + (size_t)(r * 16 + mt * 2) * (64 * 256);
  const __hip_bfloat16* Bbase =
      wb + (size_t)(net * 9) * (256 * 256) + (size_t)(nt * 128) * 256;

  // per-lane decode of the 4 A-fragment rows (output pixels)
  int bl[4], py[4], pxr[4];
#pragma unroll
  for (int mf = 0; mf < 4; ++mf) {
    int m = wm + mf * 16 + ln;
    bl[mf] = m >> 6;
    py[mf] = (m >> 3) & 7;
    pxr[mf] = m & 7;
  }
  // B fragment LDS byte offsets within one 16KB tap tile (constant all K loop)
  int boff[4][2];
#pragma unroll
  for (int nf = 0; nf < 4; ++nf) {
    int nrow = wn + nf * 16 + ln;
#pragma unroll
    for (int kk = 0; kk < 2; ++kk) {
      int sl = kk * 4 + q;
      int sp = (sl + (nrow & 7)) & 7;
      boff[nf][kk] = nrow * 128 + sp * 16;
    }
  }

  f32x4 acc[4][4];
#pragma unroll
  for (int mf = 0; mf < 4; ++mf)
#pragma unroll
    for (int nf = 0; nf < 4; ++nf)
      acc[mf][nf] = (f32x4){0.f, 0.f, 0.f, 0.f};

  const bf16x8 zero8 = {0, 0, 0, 0, 0, 0, 0, 0};

  auto stageA = [&](int c0) {
#pragma unroll
    for (int i = 0; i < 4; ++i) {
      int slot = i * 256 + tid;
      int row = slot >> 3, sp = slot & 7;
      int sl = (sp - (row & 7)) & 7;
      g2l16(Aslab + (size_t)row * 256 + c0 + sl * 8, sA + slot * 16);
    }
  };
  auto stageB = [&](int tap, int c0, int sbuf) {
    const __hip_bfloat16* Btap = Bbase + (size_t)tap * (256 * 256);
#pragma unroll
    for (int i = 0; i < 4; ++i) {
      int slot = i * 256 + tid;
      int row = slot >> 3, sp = slot & 7;
      int sl = (sp - (row & 7)) & 7;
      g2l16(Btap + (size_t)row * 256 + c0 + sl * 8,
            sB + sbuf * 16384 + slot * 16);
    }
  };

  // prologue: A(cc0) + taps 0,1  (12 loads in flight)
  stageA(0);
  stageB(0, 0, 0);
  stageB(1, 0, 1);

#pragma unroll 1
  for (int cc = 0; cc < 4; ++cc) {
    const int c0 = cc * 64;
#pragma unroll
    for (int t = 0; t < 9; ++t) {
      if (t <= 6) {
        stageB(t + 2, c0, (t + 2) % 3);
        asm volatile("s_waitcnt vmcnt(8)" ::: "memory");
      } else if (t == 7) {
        asm volatile("s_waitcnt vmcnt(4)" ::: "memory");
      } else {
        asm volatile("s_waitcnt vmcnt(0)" ::: "memory");
      }
      __builtin_amdgcn_s_barrier();  // all waves: tap t (and A) in LDS

      const int dy = t / 3 - 1, dx = t % 3 - 1;
      const char* sBt = sB + (t % 3) * 16384;

      int arow[4], avalid[4];
#pragma unroll
      for (int mf = 0; mf < 4; ++mf) {
        int sy = py[mf] + dy, sx = pxr[mf] + dx;
        int v = ((unsigned)sy < 8u) & ((unsigned)sx < 8u);
        avalid[mf] = v;
        arow[mf] = (bl[mf] << 6) + (v ? (sy * 8 + sx) : 0);
      }
#pragma unroll
      for (int kk = 0; kk < 2; ++kk) {
        bf16x8 afr[4], bfr[4];
#pragma unroll
        for (int mf = 0; mf < 4; ++mf) {
          int row = arow[mf];
          int sp = ((kk * 4 + q) + (row & 7)) & 7;
          bf16x8 v = *(const bf16x8*)(sA + row * 128 + sp * 16);
          afr[mf] = avalid[mf] ? v : zero8;
        }
#pragma unroll
        for (int nf = 0; nf < 4; ++nf)
          bfr[nf] = *(const bf16x8*)(sBt + boff[nf][kk]);
        __builtin_amdgcn_s_setprio(1);
#pragma unroll
        for (int mf = 0; mf < 4; ++mf)
#pragma unroll
          for (int nf = 0; nf < 4; ++nf)
            acc[mf][nf] = __builtin_amdgcn_mfma_f32_16x16x32_bf16(
                afr[mf], bfr[nf], acc[mf][nf], 0, 0, 0);
        __builtin_amdgcn_s_setprio(0);
      }
      __builtin_amdgcn_s_barrier();  // reads done -> slot (and sA at t=8) reusable
    }
    if (cc < 3) {  // refill pipeline for next cc (the only real bubbles)
      stageA(c0 + 64);
      stageB(0, c0 + 64, 0);
      stageB(1, c0 + 64, 1);
    }
  }

  // Epilogue: D col = lane&15 (n), row = q*4+reg (m). Each lane's 4 regs are
  // 4 consecutive x-pixels -> aligned float4 residual load + store.
  const int nbase = nt * 128 + wn;
#pragma unroll
  for (int nf = 0; nf < 4; ++nf) {
    const int n = nbase + nf * 16 + ln;
    const float cb = cbias[net * 256 + n];
#pragma unroll
    for (int mf = 0; mf < 4; ++mf) {
      int mloc = wm + mf * 16 + q * 4;
      int b = mt * 2 + (mloc >> 6);
      int px = mloc & 63;
      int yy = px >> 3, x0 = px & 7;
      size_t off =
          (((size_t)b * 256 + n) * 64 + (gi * 8 + yy)) * 64 + (gj * 8 + x0);
      f32x4 res = *(const f32x4*)(xin + off);
      f32x4 o = acc[mf][nf];
      o = o + res;
      o = o + cb;
      *(f32x4*)(outp + off) = o;
    }
  }
}

// ---------------------------------------------------------------------------
extern "C" void kernel_launch(void* const* d_in, const int* in_sizes, int n_in,
                              void* d_out, int out_size, void* d_ws,
                              size_t ws_size, hipStream_t stream) {
  const float* x      = (const float*)d_in[0];
  const float* gamma  = (const float*)d_in[1];
  const float* beta   = (const float*)d_in[2];
  const float* mean   = (const float*)d_in[3];
  const float* var    = (const float*)d_in[4];
  const float* conv_w = (const float*)d_in[5];
  const float* conv_b = (const float*)d_in[6];
  float* out = (float*)d_out;

  __hip_bfloat16* wb = (__hip_bfloat16*)d_ws;                       // 75497472 B
  __hip_bfloat16* hh = (__hip_bfloat16*)((char*)d_ws + 75497472);   // 33554432 B

  wtrans_kernel<<<dim3(32, 64), 256, 0, stream>>>(conv_w, wb);
  bnrelu_kernel<<<4096, 256, 0, stream>>>(x, gamma, beta, mean, var, hh);
  conv_kernel<<<1024, 256, 0, stream>>>(hh, wb, x, conv_b, out);
}